// Round 2
// baseline (1300.093 us; speedup 1.0000x reference)
//
#include <hip/hip_runtime.h>

// Problem constants (from reference)
constexpr int NUM_SEQS  = 32;
constexpr int KV_LEN    = 2048;
constexpr int NUM_HEADS = 16;
constexpr int HEAD_SIZE = 128;
constexpr float SCALE   = 0.08838834764831845f;

constexpr int HSTRIDE = NUM_HEADS * HEAD_SIZE;                    // floats per slot (2048)
constexpr size_t KV_PLANE = (size_t)NUM_SEQS * KV_LEN * HSTRIDE;  // elements in K plane

constexpr int NPART   = 4;               // split-K partitions per (seq, head)
constexpr int PSTRIDE = HEAD_SIZE + 2;   // per-partial record: [m, l, out[128]]

// One-pass online-softmax flash-decode.
//  - No score buffer, no mid-kernel __syncthreads: each half-wave streams its
//    positions with a running (m, l, acc) and the 8 halves merge once at the end.
//  - Software-pipelined: K and V float4 loads for group i+1 are issued before
//    computing group i -> 8 loads in flight per lane, waits land after VALU work.
//  - Block order: 16 heads of the same (seq, chunk) are adjacent in dispatch so
//    their combined reads cover each slot's contiguous 8 KB (DRAM row locality).
//  - reshape_and_cache is folded in: position t_new substitutes knew/vnew.
template <int NP>
__global__ __launch_bounds__(256, 4)
void fd_kernel(const float* __restrict__ q,
               const float* __restrict__ knew,
               const float* __restrict__ vnew,
               const float* __restrict__ kv,
               const int*  __restrict__ slot_map,
               float* __restrict__ ws,
               float* __restrict__ out)
{
    constexpr int CH  = KV_LEN / NP;     // positions per block
    constexpr int NIT = CH / 32;         // 32 positions per block-iteration

    const int bid = blockIdx.x;          // ((s*NP + c) * 16 + h)
    const int h   = bid & (NUM_HEADS - 1);
    const int scv = bid >> 4;            // s*NP + c
    const int c   = scv & (NP - 1);
    const int s   = scv / NP;
    const int sh  = s * NUM_HEADS + h;

    const int tid  = threadIdx.x;
    const int half = tid >> 5;           // 0..7
    const int lane = tid & 31;           // lane within half-wave

    const int qoff = sh * HEAD_SIZE;
    const float* kbase = kv + (size_t)s * KV_LEN * HSTRIDE + (size_t)h * HEAD_SIZE;
    const float* vbase = kbase + KV_PLANE;
    const int t_new = slot_map[s] - s * KV_LEN;   // position replaced by new token

    float4 qv = *reinterpret_cast<const float4*>(q + qoff + lane * 4);
    qv.x *= SCALE; qv.y *= SCALE; qv.z *= SCALE; qv.w *= SCALE;  // fold scale into q

    float  m   = -1e30f;
    float  l   = 0.f;
    float4 acc = make_float4(0.f, 0.f, 0.f, 0.f);

    auto kptr = [&](int t) {
        return ((t == t_new) ? (knew + qoff) : (kbase + (size_t)t * HSTRIDE)) + lane * 4;
    };
    auto vptr = [&](int t) {
        return ((t == t_new) ? (vnew + qoff) : (vbase + (size_t)t * HSTRIDE)) + lane * 4;
    };

    auto compute = [&](const float4& K0, const float4& K1, const float4& K2, const float4& K3,
                       const float4& V0, const float4& V1, const float4& V2, const float4& V3) {
        float d0 = fmaf(K0.x, qv.x, fmaf(K0.y, qv.y, fmaf(K0.z, qv.z, K0.w * qv.w)));
        float d1 = fmaf(K1.x, qv.x, fmaf(K1.y, qv.y, fmaf(K1.z, qv.z, K1.w * qv.w)));
        float d2 = fmaf(K2.x, qv.x, fmaf(K2.y, qv.y, fmaf(K2.z, qv.z, K2.w * qv.w)));
        float d3 = fmaf(K3.x, qv.x, fmaf(K3.y, qv.y, fmaf(K3.z, qv.z, K3.w * qv.w)));

        // 32-lane butterfly (xor masks <32 never cross the half-wave boundary)
        #pragma unroll
        for (int off = 16; off > 0; off >>= 1) {
            d0 += __shfl_xor(d0, off);
            d1 += __shfl_xor(d1, off);
            d2 += __shfl_xor(d2, off);
            d3 += __shfl_xor(d3, off);
        }

        const float mn  = fmaxf(fmaxf(m, fmaxf(d0, d1)), fmaxf(d2, d3));
        const float scl = __expf(m - mn);          // == 0 on first group (m = -1e30)
        const float e0  = __expf(d0 - mn);
        const float e1  = __expf(d1 - mn);
        const float e2  = __expf(d2 - mn);
        const float e3  = __expf(d3 - mn);
        m = mn;
        l = fmaf(l, scl, (e0 + e1) + (e2 + e3));

        acc.x = fmaf(e0, V0.x, fmaf(e1, V1.x, fmaf(e2, V2.x, fmaf(e3, V3.x, acc.x * scl))));
        acc.y = fmaf(e0, V0.y, fmaf(e1, V1.y, fmaf(e2, V2.y, fmaf(e3, V3.y, acc.y * scl))));
        acc.z = fmaf(e0, V0.z, fmaf(e1, V1.z, fmaf(e2, V2.z, fmaf(e3, V3.z, acc.z * scl))));
        acc.w = fmaf(e0, V0.w, fmaf(e1, V1.w, fmaf(e2, V2.w, fmaf(e3, V3.w, acc.w * scl))));
    };

    int t0 = c * CH + half * 4;

    // prologue: load group 0
    float4 kc0 = *reinterpret_cast<const float4*>(kptr(t0 + 0));
    float4 kc1 = *reinterpret_cast<const float4*>(kptr(t0 + 1));
    float4 kc2 = *reinterpret_cast<const float4*>(kptr(t0 + 2));
    float4 kc3 = *reinterpret_cast<const float4*>(kptr(t0 + 3));
    float4 vc0 = *reinterpret_cast<const float4*>(vptr(t0 + 0));
    float4 vc1 = *reinterpret_cast<const float4*>(vptr(t0 + 1));
    float4 vc2 = *reinterpret_cast<const float4*>(vptr(t0 + 2));
    float4 vc3 = *reinterpret_cast<const float4*>(vptr(t0 + 3));

    for (int it = 0; it < NIT - 1; ++it) {
        const int tn = t0 + 32;
        // prefetch group it+1 (8 loads in flight while we compute group it)
        float4 kn0 = *reinterpret_cast<const float4*>(kptr(tn + 0));
        float4 kn1 = *reinterpret_cast<const float4*>(kptr(tn + 1));
        float4 kn2 = *reinterpret_cast<const float4*>(kptr(tn + 2));
        float4 kn3 = *reinterpret_cast<const float4*>(kptr(tn + 3));
        float4 vn0 = *reinterpret_cast<const float4*>(vptr(tn + 0));
        float4 vn1 = *reinterpret_cast<const float4*>(vptr(tn + 1));
        float4 vn2 = *reinterpret_cast<const float4*>(vptr(tn + 2));
        float4 vn3 = *reinterpret_cast<const float4*>(vptr(tn + 3));

        compute(kc0, kc1, kc2, kc3, vc0, vc1, vc2, vc3);

        kc0 = kn0; kc1 = kn1; kc2 = kn2; kc3 = kn3;
        vc0 = vn0; vc1 = vn1; vc2 = vn2; vc3 = vn3;
        t0 = tn;
    }
    compute(kc0, kc1, kc2, kc3, vc0, vc1, vc2, vc3);

    // ---------------- merge the 8 half-wave partials ----------------
    __shared__ float sm[8];
    __shared__ float sl[8];
    __shared__ float part[8][HEAD_SIZE];   // 4 KB

    *reinterpret_cast<float4*>(&part[half][lane * 4]) = acc;
    if (lane == 0) { sm[half] = m; sl[half] = l; }
    __syncthreads();

    if (tid < HEAD_SIZE) {
        float M = sm[0];
        #pragma unroll
        for (int i = 1; i < 8; ++i) M = fmaxf(M, sm[i]);
        float L = 0.f, o = 0.f;
        #pragma unroll
        for (int i = 0; i < 8; ++i) {
            const float w = __expf(sm[i] - M);
            L = fmaf(sl[i], w, L);
            o = fmaf(part[i][tid], w, o);
        }
        if constexpr (NP == 1) {
            out[qoff + tid] = o / L;       // single partition == final result
        } else {
            float* rec = ws + (size_t)(sh * NP + c) * PSTRIDE;
            rec[2 + tid] = o;              // unnormalized partial
            if (tid == 0) { rec[0] = M; rec[1] = L; }
        }
    }
}

// Merge NPART partials per (seq, head): standard max-rescale combine.
__global__ __launch_bounds__(128)
void fd_reduce(const float* __restrict__ ws, float* __restrict__ out)
{
    const int sh = blockIdx.x;        // 0..511
    const int i  = threadIdx.x;       // 0..127
    const float* rec0 = ws + (size_t)sh * NPART * PSTRIDE;

    float M = -1e30f;
    #pragma unroll
    for (int c = 0; c < NPART; ++c) M = fmaxf(M, rec0[c * PSTRIDE]);

    float L = 0.f, o = 0.f;
    #pragma unroll
    for (int c = 0; c < NPART; ++c) {
        const float w = __expf(rec0[c * PSTRIDE] - M);
        L = fmaf(rec0[c * PSTRIDE + 1], w, L);
        o = fmaf(rec0[c * PSTRIDE + 2 + i], w, o);
    }
    out[sh * HEAD_SIZE + i] = o / L;
}

extern "C" void kernel_launch(void* const* d_in, const int* in_sizes, int n_in,
                              void* d_out, int out_size, void* d_ws, size_t ws_size,
                              hipStream_t stream) {
    const float* q    = (const float*)d_in[0];
    const float* k    = (const float*)d_in[1];
    const float* v    = (const float*)d_in[2];
    const float* kv   = (const float*)d_in[3];
    const int*   slot = (const int*)d_in[4];
    float* out = (float*)d_out;

    const size_t need = (size_t)NUM_SEQS * NUM_HEADS * NPART * PSTRIDE * sizeof(float);
    if (d_ws != nullptr && ws_size >= need) {
        dim3 grid1(NUM_SEQS * NUM_HEADS * NPART);   // 2048 blocks
        hipLaunchKernelGGL(fd_kernel<NPART>, grid1, dim3(256), 0, stream,
                           q, k, v, kv, slot, (float*)d_ws, out);
        dim3 grid2(NUM_SEQS * NUM_HEADS);           // tiny merge
        hipLaunchKernelGGL(fd_reduce, grid2, dim3(128), 0, stream,
                           (float*)d_ws, out);
    } else {
        // Workspace unavailable: single-partition fallback.
        dim3 grid(NUM_SEQS * NUM_HEADS);
        hipLaunchKernelGGL(fd_kernel<1>, grid, dim3(256), 0, stream,
                           q, k, v, kv, slot, nullptr, out);
    }
}